// Round 11
// baseline (355.131 us; speedup 1.0000x reference)
//
#include <hip/hip_runtime.h>
#include <hip/hip_bf16.h>
#include <math.h>

// Problem constants
#define BB 256
#define KK 32
#define DD 128
#define HH 256
#define NN 16
// d_out layout (fp32, concatenated in return order)
#define O0 ((size_t)0)
#define O1 ((size_t)33554432)
#define O2 ((size_t)37748736)
#define O3 ((size_t)71303168)

typedef float f32x4 __attribute__((ext_vector_type(4)));
typedef short s16x8 __attribute__((ext_vector_type(8)));

static __device__ __forceinline__ short f2bf(float x) {
  __hip_bfloat16 h = __float2bfloat16(x);
  return *reinterpret_cast<short*>(&h);
}
static __device__ __forceinline__ float bf2f(short s) {
  __hip_bfloat16 h;
  *reinterpret_cast<short*>(&h) = s;
  return __bfloat162float(h);
}
// pack 2 f32 -> 2 bf16 (RNE): lo16 = bf16(a), hi16 = bf16(b)
static __device__ __forceinline__ unsigned cvt_pk_bf16(float a, float b) {
  unsigned r;
  asm volatile("v_cvt_pk_bf16_f32 %0, %1, %2" : "=v"(r) : "v"(a), "v"(b));
  return r;
}
static __device__ __forceinline__ float bflo(unsigned h) {
  return __uint_as_float(h << 16);
}
static __device__ __forceinline__ float bfhi(unsigned h) {
  return __uint_as_float(h & 0xFFFF0000u);
}

// exact-erf gelu via Abramowitz-Stegun 7.1.26 (|erf err| <= 1.5e-7)
static __device__ __forceinline__ float gelu_exact(float x) {
  float ax = fabsf(x) * 0.70710678118654752f;
  float t = __builtin_amdgcn_rcpf(fmaf(0.3275911f, ax, 1.0f));
  float p = fmaf(1.061405429f, t, -1.453152027f);
  p = fmaf(p, t, 1.421413741f);
  p = fmaf(p, t, -0.284496736f);
  p = fmaf(p, t, 0.254829592f);
  p *= t;
  float e = __expf(-ax * ax);
  float er = fmaf(-p, e, 1.0f);  // erf(|x|/sqrt2)
  er = copysignf(er, x);
  return 0.5f * x * (1.0f + er);
}

// ---------------------------------------------------------------------------
// Prep: z->bf16; W1 -> transposed hi/lo bf16 [512][128]; W2 -> transposed
// hi/lo [128][256]; cbT bf16 [128][32] (n>=16 zero);
// W2cb = W2@cb^T -> hi/lo bf16 [16][256]; b2cb[n] = b2 . cb[n] (fp32).
// ---------------------------------------------------------------------------
__global__ __launch_bounds__(256) void prep_kernel(
    const float* __restrict__ z, const float* __restrict__ W1,
    const float* __restrict__ W2, const float* __restrict__ cb,
    const float* __restrict__ b2,
    short* __restrict__ zb, short* __restrict__ W1th, short* __restrict__ W1tl,
    short* __restrict__ Wh, short* __restrict__ Wl, short* __restrict__ cbT,
    short* __restrict__ Vh, short* __restrict__ Vl, float* __restrict__ b2cb) {
  const int idx = blockIdx.x * 256 + threadIdx.x;  // 1,048,576 total
  zb[idx] = f2bf(z[idx]);
  if (idx < 512 * 128) {  // W1t
    int c = idx >> 7, k = idx & 127;
    float w = (c < 256) ? W1[(size_t)k * 256 + c]
                        : W1[(size_t)(128 + k) * 256 + (c - 256)];
    short h = f2bf(w);
    W1th[idx] = h;
    W1tl[idx] = f2bf(w - bf2f(h));
  }
  if (idx < 128 * 256) {  // W2t: [c][k]
    int c = idx >> 8, k = idx & 255;
    float w = W2[(size_t)k * 128 + c];
    short h = f2bf(w);
    Wh[idx] = h;
    Wl[idx] = f2bf(w - bf2f(h));
  }
  if (idx < 128 * 32) {  // cbT [c][n], zero-padded n>=16
    int c = idx >> 5, n = idx & 31;
    cbT[idx] = (n < 16) ? f2bf(cb[(size_t)n * 128 + c]) : (short)0;
  }
  if (idx < 16 * 256) {  // W2cb [n][k] = sum_c W2[k][c]*cb[n][c]
    int n = idx >> 8, k = idx & 255;
    float s = 0.f;
#pragma unroll 4
    for (int c = 0; c < 128; ++c)
      s += W2[(size_t)k * 128 + c] * cb[(size_t)n * 128 + c];
    short h = f2bf(s);
    Vh[idx] = h;
    Vl[idx] = f2bf(s - bf2f(h));
  }
  if (idx < 16) {
    float s = 0.f;
    for (int c = 0; c < 128; ++c) s += b2[c] * cb[(size_t)idx * 128 + c];
    b2cb[idx] = s;
  }
}

// ---------------------------------------------------------------------------
// H projection via MFMA: Hcat[8192][512] = zb @ W1t^T (split-bf16), b1 folded.
// ---------------------------------------------------------------------------
__global__ __launch_bounds__(256) void hproj_mfma(
    const short* __restrict__ zb, const short* __restrict__ W1th,
    const short* __restrict__ W1tl, const float* __restrict__ b1,
    float* __restrict__ H) {
  const int tid = threadIdx.x;
  const int lane = tid & 63;
  const int wv = tid >> 6;
  const int l4 = lane >> 4, l15 = lane & 15;
  const int row0 = blockIdx.x * 32;
  const int col0 = blockIdx.y * 128 + wv * 32;

  f32x4 acc[2][2];
#pragma unroll
  for (int mt = 0; mt < 2; ++mt)
#pragma unroll
    for (int nt = 0; nt < 2; ++nt)
      acc[mt][nt] = (f32x4){0.f, 0.f, 0.f, 0.f};

#pragma unroll
  for (int ks = 0; ks < 4; ++ks) {
    const int kof = ks * 32 + l4 * 8;
    s16x8 a0 = *(const s16x8*)(zb + (size_t)(row0 + l15) * 128 + kof);
    s16x8 a1 = *(const s16x8*)(zb + (size_t)(row0 + 16 + l15) * 128 + kof);
    s16x8 bh0 = *(const s16x8*)(W1th + (size_t)(col0 + l15) * 128 + kof);
    s16x8 bh1 = *(const s16x8*)(W1th + (size_t)(col0 + 16 + l15) * 128 + kof);
    s16x8 bl0 = *(const s16x8*)(W1tl + (size_t)(col0 + l15) * 128 + kof);
    s16x8 bl1 = *(const s16x8*)(W1tl + (size_t)(col0 + 16 + l15) * 128 + kof);
    acc[0][0] = __builtin_amdgcn_mfma_f32_16x16x32_bf16(a0, bh0, acc[0][0], 0, 0, 0);
    acc[0][0] = __builtin_amdgcn_mfma_f32_16x16x32_bf16(a0, bl0, acc[0][0], 0, 0, 0);
    acc[0][1] = __builtin_amdgcn_mfma_f32_16x16x32_bf16(a0, bh1, acc[0][1], 0, 0, 0);
    acc[0][1] = __builtin_amdgcn_mfma_f32_16x16x32_bf16(a0, bl1, acc[0][1], 0, 0, 0);
    acc[1][0] = __builtin_amdgcn_mfma_f32_16x16x32_bf16(a1, bh0, acc[1][0], 0, 0, 0);
    acc[1][0] = __builtin_amdgcn_mfma_f32_16x16x32_bf16(a1, bl0, acc[1][0], 0, 0, 0);
    acc[1][1] = __builtin_amdgcn_mfma_f32_16x16x32_bf16(a1, bh1, acc[1][1], 0, 0, 0);
    acc[1][1] = __builtin_amdgcn_mfma_f32_16x16x32_bf16(a1, bl1, acc[1][1], 0, 0, 0);
  }

#pragma unroll
  for (int nt = 0; nt < 2; ++nt) {
    const int col = col0 + nt * 16 + l15;
    const float bias = (col0 < 256) ? b1[col] : 0.f;  // wave-uniform branch
#pragma unroll
    for (int mt = 0; mt < 2; ++mt)
#pragma unroll
      for (int r = 0; r < 4; ++r)
        H[(size_t)(row0 + mt * 16 + l4 * 4 + r) * 512 + col] =
            acc[mt][nt][r] + bias;
  }
}

#define MFMA16(d, a, bsrc) d = __builtin_amdgcn_mfma_f32_16x16x32_bf16(a, bsrc, d, 0, 0, 0)

// ---------------------------------------------------------------------------
// Kernel B: 128-thread blocks (2 waves), one block per (b,i).
// Each WAVE independently handles 16 j-rows end-to-end: NO barriers at all.
//  A:  gelu directly into MFMA A-fragments (registers; lane computes exactly
//      A[j=l15][k=ks*32+l4*8..+7]) -- no LDS for A
//  G:  e^T = W-frag x A-frag swapped MFMA (24/ks) + logits = A @ W2cb (3/ks)
//  E:  e fp32 -> global float4 from accumulators
//  SM: softmax wave-local (shfl over 16 n-lanes)
//  M:  m^T = cbT-frag x alpha-frag swapped MFMA (wave-private 1KB LDS transp.)
// XCD swizzle: same-b blocks share an XCD (Hj L2 reuse).
// ---------------------------------------------------------------------------
__global__ __launch_bounds__(128, 3) void pair_kernel(
    const float* __restrict__ Hcat, const short* __restrict__ Wh,
    const short* __restrict__ Wl, const float* __restrict__ b2,
    const short* __restrict__ Vh, const short* __restrict__ Vl,
    const float* __restrict__ b2cb, const short* __restrict__ cbT,
    float* __restrict__ out) {
  __shared__ short alpT[2][16 * 32];  // per-wave alpha transpose, n-padded

  const int tid = threadIdx.x;
  const int wv = tid >> 6;
  const int lane = tid & 63;
  const int l4 = lane >> 4, l15 = lane & 15;
  // bijective XCD swizzle (8192 % 8 == 0)
  const int dd = blockIdx.x;
  const int blk = (dd & 7) * 1024 + (dd >> 3);  // = b*K + i
  const int b = blk >> 5;
  const int j0 = wv * 16;  // this wave's j-rows: j0..j0+15

  // zero own alpha buffer (n>=16 pad must be 0); wave-local, no barrier
  *(uint4*)((char*)&alpT[wv][0] + lane * 16) = make_uint4(0u, 0u, 0u, 0u);

  // ---- Phase A: gelu -> A-fragments in registers ----
  s16x8 Ah[8], Al[8];
  {
    const float* hib = Hcat + (size_t)blk * 512;                        // b1 folded
    const float* hjb = Hcat + ((size_t)(b * KK + j0 + l15)) * 512 + 256;
#pragma unroll
    for (int ks = 0; ks < 8; ++ks) {
      const int k = ks * 32 + l4 * 8;
      float4 hi0 = *(const float4*)(hib + k);
      float4 hi1 = *(const float4*)(hib + k + 4);
      float4 hj0 = *(const float4*)(hjb + k);
      float4 hj1 = *(const float4*)(hjb + k + 4);
      float g0 = gelu_exact(hi0.x + hj0.x);
      float g1 = gelu_exact(hi0.y + hj0.y);
      float g2 = gelu_exact(hi0.z + hj0.z);
      float g3 = gelu_exact(hi0.w + hj0.w);
      float g4 = gelu_exact(hi1.x + hj1.x);
      float g5 = gelu_exact(hi1.y + hj1.y);
      float g6 = gelu_exact(hi1.z + hj1.z);
      float g7 = gelu_exact(hi1.w + hj1.w);
      unsigned h0 = cvt_pk_bf16(g0, g1);
      unsigned h1 = cvt_pk_bf16(g2, g3);
      unsigned h2 = cvt_pk_bf16(g4, g5);
      unsigned h3 = cvt_pk_bf16(g6, g7);
      unsigned q0 = cvt_pk_bf16(g0 - bflo(h0), g1 - bfhi(h0));
      unsigned q1 = cvt_pk_bf16(g2 - bflo(h1), g3 - bfhi(h1));
      unsigned q2 = cvt_pk_bf16(g4 - bflo(h2), g5 - bfhi(h2));
      unsigned q3 = cvt_pk_bf16(g6 - bflo(h3), g7 - bfhi(h3));
      unsigned hv[4] = {h0, h1, h2, h3};
      unsigned lv[4] = {q0, q1, q2, q3};
      Ah[ks] = *(const s16x8*)hv;
      Al[ks] = *(const s16x8*)lv;
    }
  }

  // ---- Phase G: swapped e-GEMM + logits (all in registers, no branches) ----
  f32x4 eacc[8];
#pragma unroll
  for (int nt = 0; nt < 8; ++nt) eacc[nt] = (f32x4){0.f, 0.f, 0.f, 0.f};
  f32x4 lacc = (f32x4){0.f, 0.f, 0.f, 0.f};

  const size_t wk0 = (size_t)l15 * 256 + l4 * 8;  // [col][k] frag base
#pragma unroll
  for (int ks = 0; ks < 8; ++ks) {
    const int ko = ks * 32;
    // logits: lacc[j-rows x n] += A @ V  (V = W2@cb^T, [n][k])
    s16x8 vh = *(const s16x8*)(Vh + wk0 + ko);
    s16x8 vl = *(const s16x8*)(Vl + wk0 + ko);
    MFMA16(lacc, Ah[ks], vh);
    MFMA16(lacc, Al[ks], vh);
    MFMA16(lacc, Ah[ks], vl);
    // e^T tiles: lane ends holding e[j=l15][c = nt*16 + l4*4 .. +3]
#pragma unroll
    for (int nt = 0; nt < 8; ++nt) {
      const size_t g = (size_t)(nt * 16) * 256 + wk0 + ko;
      s16x8 wh = *(const s16x8*)(Wh + g);
      s16x8 wl = *(const s16x8*)(Wl + g);
      MFMA16(eacc[nt], wh, Ah[ks]);
      MFMA16(eacc[nt], wh, Al[ks]);
      MFMA16(eacc[nt], wl, Ah[ks]);
    }
  }

  // ---- Phase E: +b2, e -> global (float4 per nt) ----
  {
    float* eg = out + O2 + (size_t)blk * (KK * DD) + (size_t)(j0 + l15) * DD;
#pragma unroll
    for (int nt = 0; nt < 8; ++nt) {
      const float4 bq = *(const float4*)(b2 + nt * 16 + l4 * 4);
      float4 v = make_float4(eacc[nt][0] + bq.x, eacc[nt][1] + bq.y,
                             eacc[nt][2] + bq.z, eacc[nt][3] + bq.w);
      *(float4*)(eg + nt * 16 + l4 * 4) = v;
    }
  }

  // ---- Phase SM: softmax (lane holds logit[j=j0+l4*4+r][n=l15]) ----
  {
    const float bcv = b2cb[l15];
    float* lg_out = out + O3 + (size_t)blk * (KK * NN);
    float* ag_out = out + O1 + (size_t)blk * (KK * NN);
#pragma unroll
    for (int r = 0; r < 4; ++r) {
      const int row = j0 + l4 * 4 + r;
      float lg = (lacc[r] + bcv) * 10.0f;
      float mx = lg;
#pragma unroll
      for (int m = 1; m < 16; m <<= 1) mx = fmaxf(mx, __shfl_xor(mx, m));
      float p = __expf(lg - mx);
      float s = p;
#pragma unroll
      for (int m = 1; m < 16; m <<= 1) s += __shfl_xor(s, m);
      float a = p / s;
      lg_out[row * 16 + l15] = lg;
      ag_out[row * 16 + l15] = a;
      alpT[wv][(l4 * 4 + r) * 32 + l15] = f2bf(a);  // wave-local transpose buf
    }
  }

  // ---- Phase M: m^T = cbT x alpha (swapped; wave-local LDS read) ----
  {
    s16x8 af = *(const s16x8*)(&alpT[wv][l15 * 32 + l4 * 8]);
    float* mg = out + O0 + (size_t)blk * (KK * DD) + (size_t)(j0 + l15) * DD;
#pragma unroll
    for (int nt = 0; nt < 8; ++nt) {
      s16x8 cf = *(const s16x8*)(cbT + (size_t)(nt * 16 + l15) * 32 + l4 * 8);
      f32x4 mac = (f32x4){0.f, 0.f, 0.f, 0.f};
      MFMA16(mac, cf, af);  // D[c][j]: lane holds m[j=l15][c = nt*16+l4*4+r]
      *(float4*)(mg + nt * 16 + l4 * 4) = *(float4*)&mac;
    }
  }
}

extern "C" void kernel_launch(void* const* d_in, const int* in_sizes, int n_in,
                              void* d_out, int out_size, void* d_ws, size_t ws_size,
                              hipStream_t stream) {
  const float* z  = (const float*)d_in[0];   // (256,32,128)
  const float* W1 = (const float*)d_in[1];   // (256,256)
  const float* b1 = (const float*)d_in[2];   // (256,)
  const float* W2 = (const float*)d_in[3];   // (256,128)
  const float* b2 = (const float*)d_in[4];   // (128,)
  const float* cb = (const float*)d_in[5];   // (16,128)
  float* out = (float*)d_out;

  // ws: Hcat fp32 [8192][512] | zb | W1th | W1tl | Wh | Wl | cbT | Vh | Vl | b2cb
  float* Hcat = (float*)d_ws;
  short* zb   = (short*)(Hcat + (size_t)8192 * 512);
  short* W1th = zb + (size_t)1048576;
  short* W1tl = W1th + (size_t)65536;
  short* Wh   = W1tl + (size_t)65536;
  short* Wl   = Wh + (size_t)32768;
  short* cbT  = Wl + (size_t)32768;
  short* Vh   = cbT + (size_t)4096;
  short* Vl   = Vh + (size_t)4096;
  float* b2cb = (float*)(Vl + (size_t)4096);

  prep_kernel<<<4096, 256, 0, stream>>>(z, W1, W2, cb, b2, zb, W1th, W1tl, Wh,
                                        Wl, cbT, Vh, Vl, b2cb);
  hproj_mfma<<<dim3(256, 4), 256, 0, stream>>>(zb, W1th, W1tl, b1, Hcat);
  pair_kernel<<<BB * KK, 128, 0, stream>>>(Hcat, Wh, Wl, b2, Vh, Vl, b2cb,
                                           cbT, out);
}

// Round 12
// 218.774 us; speedup vs baseline: 1.6233x; 1.6233x over previous
//
#include <hip/hip_runtime.h>
#include <hip/hip_bf16.h>
#include <math.h>

// Problem constants
#define BB 256
#define KK 32
#define DD 128
#define HH 256
#define NN 16
// d_out layout (fp32, concatenated in return order)
#define O0 ((size_t)0)
#define O1 ((size_t)33554432)
#define O2 ((size_t)37748736)
#define O3 ((size_t)71303168)

typedef float f32x4 __attribute__((ext_vector_type(4)));
typedef short s16x8 __attribute__((ext_vector_type(8)));

static __device__ __forceinline__ short f2bf(float x) {
  __hip_bfloat16 h = __float2bfloat16(x);
  return *reinterpret_cast<short*>(&h);
}
static __device__ __forceinline__ float bf2f(short s) {
  __hip_bfloat16 h;
  *reinterpret_cast<short*>(&h) = s;
  return __bfloat162float(h);
}
// pack 2 f32 -> 2 bf16 (RNE): lo16 = bf16(a), hi16 = bf16(b)
static __device__ __forceinline__ unsigned cvt_pk_bf16(float a, float b) {
  unsigned r;
  asm volatile("v_cvt_pk_bf16_f32 %0, %1, %2" : "=v"(r) : "v"(a), "v"(b));
  return r;
}

// exact-erf gelu via Abramowitz-Stegun 7.1.26 (|erf err| <= 1.5e-7)
static __device__ __forceinline__ float gelu_exact(float x) {
  float ax = fabsf(x) * 0.70710678118654752f;
  float t = __builtin_amdgcn_rcpf(fmaf(0.3275911f, ax, 1.0f));
  float p = fmaf(1.061405429f, t, -1.453152027f);
  p = fmaf(p, t, 1.421413741f);
  p = fmaf(p, t, -0.284496736f);
  p = fmaf(p, t, 0.254829592f);
  p *= t;
  float e = __expf(-ax * ax);
  float er = fmaf(-p, e, 1.0f);  // erf(|x|/sqrt2)
  er = copysignf(er, x);
  return 0.5f * x * (1.0f + er);
}

// ---------------------------------------------------------------------------
// Prep: z->bf16; W1 -> transposed hi/lo bf16 [512][128]; W2 -> transposed
// hi/lo [128][256]; cbT bf16 [128][32] (n>=16 zero);
// W2cb = W2@cb^T -> hi/lo bf16 [16][256]; b2cb[n] = b2 . cb[n] (fp32).
// ---------------------------------------------------------------------------
__global__ __launch_bounds__(256) void prep_kernel(
    const float* __restrict__ z, const float* __restrict__ W1,
    const float* __restrict__ W2, const float* __restrict__ cb,
    const float* __restrict__ b2,
    short* __restrict__ zb, short* __restrict__ W1th, short* __restrict__ W1tl,
    short* __restrict__ Wh, short* __restrict__ Wl, short* __restrict__ cbT,
    short* __restrict__ Vh, short* __restrict__ Vl, float* __restrict__ b2cb) {
  const int idx = blockIdx.x * 256 + threadIdx.x;  // 1,048,576 total
  zb[idx] = f2bf(z[idx]);
  if (idx < 512 * 128) {  // W1t
    int c = idx >> 7, k = idx & 127;
    float w = (c < 256) ? W1[(size_t)k * 256 + c]
                        : W1[(size_t)(128 + k) * 256 + (c - 256)];
    short h = f2bf(w);
    W1th[idx] = h;
    W1tl[idx] = f2bf(w - bf2f(h));
  }
  if (idx < 128 * 256) {  // W2t: [c][k]
    int c = idx >> 8, k = idx & 255;
    float w = W2[(size_t)k * 128 + c];
    short h = f2bf(w);
    Wh[idx] = h;
    Wl[idx] = f2bf(w - bf2f(h));
  }
  if (idx < 128 * 32) {  // cbT [c][n], zero-padded n>=16
    int c = idx >> 5, n = idx & 31;
    cbT[idx] = (n < 16) ? f2bf(cb[(size_t)n * 128 + c]) : (short)0;
  }
  if (idx < 16 * 256) {  // W2cb [n][k] = sum_c W2[k][c]*cb[n][c]
    int n = idx >> 8, k = idx & 255;
    float s = 0.f;
#pragma unroll 4
    for (int c = 0; c < 128; ++c)
      s += W2[(size_t)k * 128 + c] * cb[(size_t)n * 128 + c];
    short h = f2bf(s);
    Vh[idx] = h;
    Vl[idx] = f2bf(s - bf2f(h));
  }
  if (idx < 16) {
    float s = 0.f;
    for (int c = 0; c < 128; ++c) s += b2[c] * cb[(size_t)idx * 128 + c];
    b2cb[idx] = s;
  }
}

// ---------------------------------------------------------------------------
// H projection via MFMA: Hcat[8192][512] = zb @ W1t^T (split-bf16), b1 folded.
// ---------------------------------------------------------------------------
__global__ __launch_bounds__(256) void hproj_mfma(
    const short* __restrict__ zb, const short* __restrict__ W1th,
    const short* __restrict__ W1tl, const float* __restrict__ b1,
    float* __restrict__ H) {
  const int tid = threadIdx.x;
  const int lane = tid & 63;
  const int wv = tid >> 6;
  const int l4 = lane >> 4, l15 = lane & 15;
  const int row0 = blockIdx.x * 32;
  const int col0 = blockIdx.y * 128 + wv * 32;

  f32x4 acc[2][2];
#pragma unroll
  for (int mt = 0; mt < 2; ++mt)
#pragma unroll
    for (int nt = 0; nt < 2; ++nt)
      acc[mt][nt] = (f32x4){0.f, 0.f, 0.f, 0.f};

#pragma unroll
  for (int ks = 0; ks < 4; ++ks) {
    const int kof = ks * 32 + l4 * 8;
    s16x8 a0 = *(const s16x8*)(zb + (size_t)(row0 + l15) * 128 + kof);
    s16x8 a1 = *(const s16x8*)(zb + (size_t)(row0 + 16 + l15) * 128 + kof);
    s16x8 bh0 = *(const s16x8*)(W1th + (size_t)(col0 + l15) * 128 + kof);
    s16x8 bh1 = *(const s16x8*)(W1th + (size_t)(col0 + 16 + l15) * 128 + kof);
    s16x8 bl0 = *(const s16x8*)(W1tl + (size_t)(col0 + l15) * 128 + kof);
    s16x8 bl1 = *(const s16x8*)(W1tl + (size_t)(col0 + 16 + l15) * 128 + kof);
    acc[0][0] = __builtin_amdgcn_mfma_f32_16x16x32_bf16(a0, bh0, acc[0][0], 0, 0, 0);
    acc[0][0] = __builtin_amdgcn_mfma_f32_16x16x32_bf16(a0, bl0, acc[0][0], 0, 0, 0);
    acc[0][1] = __builtin_amdgcn_mfma_f32_16x16x32_bf16(a0, bh1, acc[0][1], 0, 0, 0);
    acc[0][1] = __builtin_amdgcn_mfma_f32_16x16x32_bf16(a0, bl1, acc[0][1], 0, 0, 0);
    acc[1][0] = __builtin_amdgcn_mfma_f32_16x16x32_bf16(a1, bh0, acc[1][0], 0, 0, 0);
    acc[1][0] = __builtin_amdgcn_mfma_f32_16x16x32_bf16(a1, bl0, acc[1][0], 0, 0, 0);
    acc[1][1] = __builtin_amdgcn_mfma_f32_16x16x32_bf16(a1, bh1, acc[1][1], 0, 0, 0);
    acc[1][1] = __builtin_amdgcn_mfma_f32_16x16x32_bf16(a1, bl1, acc[1][1], 0, 0, 0);
  }

#pragma unroll
  for (int nt = 0; nt < 2; ++nt) {
    const int col = col0 + nt * 16 + l15;
    const float bias = (col0 < 256) ? b1[col] : 0.f;  // wave-uniform branch
#pragma unroll
    for (int mt = 0; mt < 2; ++mt)
#pragma unroll
      for (int r = 0; r < 4; ++r)
        H[(size_t)(row0 + mt * 16 + l4 * 4 + r) * 512 + col] =
            acc[mt][nt][r] + bias;
  }
}

#define MFMA16(d, a, bsrc) d = __builtin_amdgcn_mfma_f32_16x16x32_bf16(a, bsrc, d, 0, 0, 0)

// ---------------------------------------------------------------------------
// Kernel B: one block (4 waves) per (b,i); all 32 j's. TWO barriers.
//  A:  gelu(Hi+Hj) -> split bf16 in swizzled LDS
//  G:  swapped e-GEMM (12 MFMA/ks, clean loop)
//  E:  e fp32 -> global float4 straight from accumulators (no LDS)
//  L:  logits = A @ (W2 cb^T) via MFMA, K=256 (waves 0,1; A re-read from LDS)
//  SM: softmax in-register (waves 0,1)
//  M:  m^T = cbT x alpha^T swapped MFMA -> float4 stores (all 4 waves)
// XCD swizzle: same-b blocks share an XCD (Hj L2 reuse).
// ---------------------------------------------------------------------------
__global__ __launch_bounds__(256, 4) void pair_kernel(
    const float* __restrict__ Hcat, const short* __restrict__ Wh,
    const short* __restrict__ Wl, const float* __restrict__ b2,
    const short* __restrict__ Vh, const short* __restrict__ Vl,
    const float* __restrict__ b2cb, const short* __restrict__ cbT,
    float* __restrict__ out) {
  __shared__ short sAh[32 * 256];  // 16 KB gelu hi split, XOR-swizzled
  __shared__ short sAl[32 * 256];  // 16 KB gelu lo split (alive through L)
  __shared__ short sAlp[32 * 32];  // 2 KB alpha^T bf16, n zero-padded to 32

  const int tid = threadIdx.x;
  // bijective XCD swizzle (8192 % 8 == 0): same-b blocks share an XCD
  const int dd = blockIdx.x;
  const int blk = (dd & 7) * 1024 + (dd >> 3);  // = b*K + i
  const int b = blk >> 5;

  // zero-init alpha buffer (pad cols must be 0)
  ((unsigned*)sAlp)[tid] = 0u;
  ((unsigned*)sAlp)[tid + 256] = 0u;

  // ---- Phase A: gelu + split-bf16 into swizzled LDS (b1 pre-folded) ----
  {
    const int k0 = (tid & 127) * 2;
    const int pb = (tid >> 7) * 16;
    const float2 hiv = *(const float2*)(Hcat + (size_t)blk * 512 + k0);
    const float hx = hiv.x;
    const float hy = hiv.y;
    const float* hjp = Hcat + ((size_t)b * KK + pb) * 512 + 256 + k0;
    unsigned* aH = (unsigned*)sAh;
    unsigned* aL = (unsigned*)sAl;
    const int cw = tid & 127;
#pragma unroll 4
    for (int p = 0; p < 16; ++p) {
      const int row = pb + p;
      float2 hj = *(const float2*)(hjp + (size_t)p * 512);
      float g0 = gelu_exact(hx + hj.x);
      float g1 = gelu_exact(hy + hj.y);
      unsigned h01 = cvt_pk_bf16(g0, g1);
      float h0f = __uint_as_float(h01 << 16);
      float h1f = __uint_as_float(h01 & 0xFFFF0000u);
      unsigned l01 = cvt_pk_bf16(g0 - h0f, g1 - h1f);
      const int wi = row * 128 + ((cw ^ ((row & 7) << 2)));
      aH[wi] = h01;
      aL[wi] = l01;
    }
  }
  __syncthreads();  // barrier 1

  // ---- Phase G: swapped e-GEMM (e^T fragments, clean loop) ----
  const int lane = tid & 63;
  const int wv = tid >> 6;  // wave owns e-cols nb..nb+31
  const int nb = wv * 32;
  const int l4 = lane >> 4;
  const int l15 = lane & 15;

  // eacc[w][a]: lane holds e[row = a*16 + l15][cols = nb + w*16 + l4*4 .. +3]
  f32x4 eacc[2][2];
#pragma unroll
  for (int w = 0; w < 2; ++w)
#pragma unroll
    for (int a = 0; a < 2; ++a)
      eacc[w][a] = (f32x4){0.f, 0.f, 0.f, 0.f};

  const int sw = (l15 & 7) << 4;
  const char* pAh = (const char*)sAh;
  const char* pAl = (const char*)sAl;
  const size_t gB0 = (size_t)(nb + l15) * 256 + l4 * 8;

#pragma unroll
  for (int ks = 0; ks < 8; ++ks) {
    const int cbyte = ks * 64 + l4 * 16;
    const int o0 = l15 * 512 + (cbyte ^ sw);
    const int o1 = (16 + l15) * 512 + (cbyte ^ sw);
    s16x8 ah0 = *(const s16x8*)(pAh + o0);
    s16x8 ah1 = *(const s16x8*)(pAh + o1);
    s16x8 al0 = *(const s16x8*)(pAl + o0);
    s16x8 al1 = *(const s16x8*)(pAl + o1);
    const size_t g0 = gB0 + ks * 32;
    const size_t g1 = g0 + 16 * 256;
    s16x8 bh0 = *(const s16x8*)(Wh + g0);
    s16x8 bh1 = *(const s16x8*)(Wh + g1);
    s16x8 bl0 = *(const s16x8*)(Wl + g0);
    s16x8 bl1 = *(const s16x8*)(Wl + g1);

    // e^T = W^T A^T, 3-pass split: (Wh,Ah)+(Wh,Al)+(Wl,Ah)
    MFMA16(eacc[0][0], bh0, ah0); MFMA16(eacc[0][0], bh0, al0);
    MFMA16(eacc[0][0], bl0, ah0);
    MFMA16(eacc[0][1], bh0, ah1); MFMA16(eacc[0][1], bh0, al1);
    MFMA16(eacc[0][1], bl0, ah1);
    MFMA16(eacc[1][0], bh1, ah0); MFMA16(eacc[1][0], bh1, al0);
    MFMA16(eacc[1][0], bl1, ah0);
    MFMA16(eacc[1][1], bh1, ah1); MFMA16(eacc[1][1], bh1, al1);
    MFMA16(eacc[1][1], bl1, ah1);
  }

  // ---- Phase E: +b2, e -> global float4 (no LDS round trip) ----
  {
    const float4 b2q0 = *(const float4*)(b2 + nb + l4 * 4);
    const float4 b2q1 = *(const float4*)(b2 + nb + 16 + l4 * 4);
    float* eg = out + O2 + (size_t)blk * (KK * DD);
#pragma unroll
    for (int a = 0; a < 2; ++a) {
      const int row = a * 16 + l15;
      float4 v0 = make_float4(eacc[0][a][0] + b2q0.x, eacc[0][a][1] + b2q0.y,
                              eacc[0][a][2] + b2q0.z, eacc[0][a][3] + b2q0.w);
      float4 v1 = make_float4(eacc[1][a][0] + b2q1.x, eacc[1][a][1] + b2q1.y,
                              eacc[1][a][2] + b2q1.z, eacc[1][a][3] + b2q1.w);
      *(float4*)(eg + row * 128 + nb + l4 * 4) = v0;
      *(float4*)(eg + row * 128 + nb + 16 + l4 * 4) = v1;
    }
  }

  // ---- Phase L: logits = A @ V (K=256), waves 0,1; A re-read from LDS ----
  // ---- Phase SM: softmax in-register; write logits/alpha ----
  if (wv < 2) {
    f32x4 lacc = (f32x4){0.f, 0.f, 0.f, 0.f};
    const int rowa = wv * 16 + l15;      // (rowa & 7) == (l15 & 7) -> same sw
    const int obase = rowa * 512;
    const size_t gV0 = (size_t)l15 * 256 + l4 * 8;
#pragma unroll
    for (int ks = 0; ks < 8; ++ks) {
      const int cbyte = ks * 64 + l4 * 16;
      const int o = obase + (cbyte ^ sw);
      s16x8 ah = *(const s16x8*)(pAh + o);
      s16x8 al = *(const s16x8*)(pAl + o);
      s16x8 vh = *(const s16x8*)(Vh + gV0 + ks * 32);
      s16x8 vl = *(const s16x8*)(Vl + gV0 + ks * 32);
      MFMA16(lacc, ah, vh);
      MFMA16(lacc, al, vh);
      MFMA16(lacc, ah, vl);
    }
    const float bcv = b2cb[l15];
    float* lg_out = out + O3 + (size_t)blk * (KK * NN);
    float* ag_out = out + O1 + (size_t)blk * (KK * NN);
#pragma unroll
    for (int r = 0; r < 4; ++r) {
      const int row = wv * 16 + l4 * 4 + r;
      float lg = (lacc[r] + bcv) * 10.0f;
      float mx = lg;
#pragma unroll
      for (int m = 1; m < 16; m <<= 1) mx = fmaxf(mx, __shfl_xor(mx, m));
      float p = __expf(lg - mx);
      float s = p;
#pragma unroll
      for (int m = 1; m < 16; m <<= 1) s += __shfl_xor(s, m);
      float a = p / s;
      lg_out[row * 16 + l15] = lg;
      ag_out[row * 16 + l15] = a;
      sAlp[row * 32 + l15] = f2bf(a);  // alpha^T fragment layout
    }
  }
  __syncthreads();  // barrier 2

  // ---- Phase M: m^T = cbT x alpha^T (swapped), float4 stores ----
  // wave wv covers c-tiles {wv, wv+4} for both j-tiles: 4 MFMA + 4 float4.
  {
#pragma unroll
    for (int jt = 0; jt < 2; ++jt) {
      s16x8 af = *(const s16x8*)(sAlp + (jt * 16 + l15) * 32 + l4 * 8);
      float* mg = out + O0 + (size_t)blk * (KK * DD) + (size_t)(jt * 16 + l15) * DD;
#pragma unroll
      for (int cp = 0; cp < 2; ++cp) {
        const int cc = wv + cp * 4;
        s16x8 cf = *(const s16x8*)(cbT + (size_t)(cc * 16 + l15) * 32 + l4 * 8);
        f32x4 mac = (f32x4){0.f, 0.f, 0.f, 0.f};
        MFMA16(mac, cf, af);  // lane: m[j = jt*16+l15][c = cc*16 + l4*4 + r]
        *(float4*)(mg + cc * 16 + l4 * 4) = *(float4*)&mac;
      }
    }
  }
}

extern "C" void kernel_launch(void* const* d_in, const int* in_sizes, int n_in,
                              void* d_out, int out_size, void* d_ws, size_t ws_size,
                              hipStream_t stream) {
  const float* z  = (const float*)d_in[0];   // (256,32,128)
  const float* W1 = (const float*)d_in[1];   // (256,256)
  const float* b1 = (const float*)d_in[2];   // (256,)
  const float* W2 = (const float*)d_in[3];   // (256,128)
  const float* b2 = (const float*)d_in[4];   // (128,)
  const float* cb = (const float*)d_in[5];   // (16,128)
  float* out = (float*)d_out;

  // ws: Hcat fp32 [8192][512] | zb | W1th | W1tl | Wh | Wl | cbT | Vh | Vl | b2cb
  float* Hcat = (float*)d_ws;
  short* zb   = (short*)(Hcat + (size_t)8192 * 512);
  short* W1th = zb + (size_t)1048576;
  short* W1tl = W1th + (size_t)65536;
  short* Wh   = W1tl + (size_t)65536;
  short* Wl   = Wh + (size_t)32768;
  short* cbT  = Wl + (size_t)32768;
  short* Vh   = cbT + (size_t)4096;
  short* Vl   = Vh + (size_t)4096;
  float* b2cb = (float*)(Vl + (size_t)4096);

  prep_kernel<<<4096, 256, 0, stream>>>(z, W1, W2, cb, b2, zb, W1th, W1tl, Wh,
                                        Wl, cbT, Vh, Vl, b2cb);
  hproj_mfma<<<dim3(256, 4), 256, 0, stream>>>(zb, W1th, W1tl, b1, Hcat);
  pair_kernel<<<BB * KK, 256, 0, stream>>>(Hcat, Wh, Wl, b2, Vh, Vl, b2cb,
                                           cbT, out);
}

// Round 13
// 202.843 us; speedup vs baseline: 1.7508x; 1.0785x over previous
//
#include <hip/hip_runtime.h>
#include <hip/hip_bf16.h>
#include <math.h>

// Problem constants
#define BB 256
#define KK 32
#define DD 128
#define HH 256
#define NN 16
// d_out layout (fp32, concatenated in return order)
#define O0 ((size_t)0)
#define O1 ((size_t)33554432)
#define O2 ((size_t)37748736)
#define O3 ((size_t)71303168)

typedef float f32x4 __attribute__((ext_vector_type(4)));
typedef short s16x8 __attribute__((ext_vector_type(8)));

static __device__ __forceinline__ short f2bf(float x) {
  __hip_bfloat16 h = __float2bfloat16(x);
  return *reinterpret_cast<short*>(&h);
}
static __device__ __forceinline__ float bf2f(short s) {
  __hip_bfloat16 h;
  *reinterpret_cast<short*>(&h) = s;
  return __bfloat162float(h);
}
// pack 2 f32 -> 2 bf16 (RNE): lo16=bf16(a), hi16=bf16(b)
static __device__ __forceinline__ unsigned cvt_pk_bf16(float a, float b) {
  unsigned r;
  asm volatile("v_cvt_pk_bf16_f32 %0, %1, %2" : "=v"(r) : "v"(a), "v"(b));
  return r;
}

// exact-erf gelu via Abramowitz-Stegun 7.1.26 (|erf err| <= 1.5e-7)
static __device__ __forceinline__ float gelu_exact(float x) {
  float ax = fabsf(x) * 0.70710678118654752f;
  float t = __builtin_amdgcn_rcpf(fmaf(0.3275911f, ax, 1.0f));
  float p = fmaf(1.061405429f, t, -1.453152027f);
  p = fmaf(p, t, 1.421413741f);
  p = fmaf(p, t, -0.284496736f);
  p = fmaf(p, t, 0.254829592f);
  p *= t;
  float e = __expf(-ax * ax);
  float er = fmaf(-p, e, 1.0f);  // erf(|x|/sqrt2)
  er = copysignf(er, x);
  return 0.5f * x * (1.0f + er);
}

// ---------------------------------------------------------------------------
// Prep: z -> bf16; W1 -> transposed hi/lo bf16 [512][128];
//       W2 -> transposed hi/lo bf16 [128][256]; cb -> hi/lo [n][k];
//       cbT -> bf16 [c 128][n 32] (n>=16 zero, for Phase M MFMA).
// ---------------------------------------------------------------------------
__global__ __launch_bounds__(256) void prep_kernel(
    const float* __restrict__ z, const float* __restrict__ W1,
    const float* __restrict__ W2, const float* __restrict__ cb,
    short* __restrict__ zb, short* __restrict__ W1th, short* __restrict__ W1tl,
    short* __restrict__ Wh, short* __restrict__ Wl,
    short* __restrict__ cbh, short* __restrict__ cbl, short* __restrict__ cbT) {
  const int idx = blockIdx.x * 256 + threadIdx.x;  // 1,048,576 total
  zb[idx] = f2bf(z[idx]);
  if (idx < 512 * 128) {  // W1t
    int c = idx >> 7, k = idx & 127;
    float w = (c < 256) ? W1[(size_t)k * 256 + c]
                        : W1[(size_t)(128 + k) * 256 + (c - 256)];
    short h = f2bf(w);
    W1th[idx] = h;
    W1tl[idx] = f2bf(w - bf2f(h));
  }
  if (idx < 128 * 256) {  // W2t: [c][k]
    int c = idx >> 8, k = idx & 255;
    float w = W2[(size_t)k * 128 + c];
    short h = f2bf(w);
    Wh[idx] = h;
    Wl[idx] = f2bf(w - bf2f(h));
  }
  if (idx < 2048) {  // cb [n][k] splits
    float v = cb[idx];
    short h = f2bf(v);
    cbh[idx] = h;
    cbl[idx] = f2bf(v - bf2f(h));
  }
  if (idx < 128 * 32) {  // cbT [c][n], zero-padded n>=16
    int c = idx >> 5, n = idx & 31;
    cbT[idx] = (n < 16) ? f2bf(cb[(size_t)n * 128 + c]) : (short)0;
  }
}

// ---------------------------------------------------------------------------
// H projection via MFMA: Hcat[8192][512] = zb @ W1t^T (split-bf16), b1 folded.
// ---------------------------------------------------------------------------
__global__ __launch_bounds__(256) void hproj_mfma(
    const short* __restrict__ zb, const short* __restrict__ W1th,
    const short* __restrict__ W1tl, const float* __restrict__ b1,
    float* __restrict__ H) {
  const int tid = threadIdx.x;
  const int lane = tid & 63;
  const int wv = tid >> 6;
  const int l4 = lane >> 4, l15 = lane & 15;
  const int row0 = blockIdx.x * 32;
  const int col0 = blockIdx.y * 128 + wv * 32;

  f32x4 acc[2][2];
#pragma unroll
  for (int mt = 0; mt < 2; ++mt)
#pragma unroll
    for (int nt = 0; nt < 2; ++nt)
      acc[mt][nt] = (f32x4){0.f, 0.f, 0.f, 0.f};

#pragma unroll
  for (int ks = 0; ks < 4; ++ks) {
    const int kof = ks * 32 + l4 * 8;
    s16x8 a0 = *(const s16x8*)(zb + (size_t)(row0 + l15) * 128 + kof);
    s16x8 a1 = *(const s16x8*)(zb + (size_t)(row0 + 16 + l15) * 128 + kof);
    s16x8 bh0 = *(const s16x8*)(W1th + (size_t)(col0 + l15) * 128 + kof);
    s16x8 bh1 = *(const s16x8*)(W1th + (size_t)(col0 + 16 + l15) * 128 + kof);
    s16x8 bl0 = *(const s16x8*)(W1tl + (size_t)(col0 + l15) * 128 + kof);
    s16x8 bl1 = *(const s16x8*)(W1tl + (size_t)(col0 + 16 + l15) * 128 + kof);
    acc[0][0] = __builtin_amdgcn_mfma_f32_16x16x32_bf16(a0, bh0, acc[0][0], 0, 0, 0);
    acc[0][0] = __builtin_amdgcn_mfma_f32_16x16x32_bf16(a0, bl0, acc[0][0], 0, 0, 0);
    acc[0][1] = __builtin_amdgcn_mfma_f32_16x16x32_bf16(a0, bh1, acc[0][1], 0, 0, 0);
    acc[0][1] = __builtin_amdgcn_mfma_f32_16x16x32_bf16(a0, bl1, acc[0][1], 0, 0, 0);
    acc[1][0] = __builtin_amdgcn_mfma_f32_16x16x32_bf16(a1, bh0, acc[1][0], 0, 0, 0);
    acc[1][0] = __builtin_amdgcn_mfma_f32_16x16x32_bf16(a1, bl0, acc[1][0], 0, 0, 0);
    acc[1][1] = __builtin_amdgcn_mfma_f32_16x16x32_bf16(a1, bh1, acc[1][1], 0, 0, 0);
    acc[1][1] = __builtin_amdgcn_mfma_f32_16x16x32_bf16(a1, bl1, acc[1][1], 0, 0, 0);
  }

#pragma unroll
  for (int nt = 0; nt < 2; ++nt) {
    const int col = col0 + nt * 16 + l15;
    const float bias = (col0 < 256) ? b1[col] : 0.f;  // wave-uniform branch
#pragma unroll
    for (int mt = 0; mt < 2; ++mt)
#pragma unroll
      for (int r = 0; r < 4; ++r)
        H[(size_t)(row0 + mt * 16 + l4 * 4 + r) * 512 + col] =
            acc[mt][nt][r] + bias;
  }
}

#define MFMA16(d, a, bsrc) d = __builtin_amdgcn_mfma_f32_16x16x32_bf16(a, bsrc, d, 0, 0, 0)

// ---------------------------------------------------------------------------
// Kernel B (r10 structure + swapped Phase M): one block (4 waves) per (b,i).
//  A:  gelu(Hi+Hj) -> split bf16 in swizzled LDS
//  G:  swapped e-GEMM (12 MFMA/ks, clean loop)
//  E:  e fp32 -> global as dwordx4; e splits -> LDS via b64 writes
//  L:  logits = e @ cb^T via MFMA K=128 (waves 0,1), softmax in-register
//  M:  m^T = cbT x alpha^T swapped MFMA -> float4 stores (all 4 waves)
// XCD swizzle: same-b blocks share an XCD (Hj L2 reuse; FETCH 37->9 MB).
// ---------------------------------------------------------------------------
__global__ __launch_bounds__(256, 4) void pair_kernel(
    const float* __restrict__ Hcat, const short* __restrict__ Wh,
    const short* __restrict__ Wl, const float* __restrict__ b2,
    const short* __restrict__ cbh, const short* __restrict__ cbl,
    const short* __restrict__ cbT, float* __restrict__ out) {
  __shared__ short sAh[32 * 256];  // 16 KB gelu hi split, XOR-swizzled
  __shared__ union {
    short Al[32 * 256];  // 16 KB gelu lo split (dead after G)
    struct { short Eh[32 * 128]; short El[32 * 128]; } e;  // e splits, swizzled
  } u;
  __shared__ short sAlp[32 * 32];  // 2 KB alpha bf16, n zero-padded to 32

  const int tid = threadIdx.x;
  // bijective XCD swizzle (8192 % 8 == 0): same-b blocks share an XCD
  const int dd = blockIdx.x;
  const int blk = (dd & 7) * 1024 + (dd >> 3);  // = b*K + i
  const int b = blk >> 5;

  // zero-init alpha buffer (pad cols must be 0)
  ((unsigned*)sAlp)[tid] = 0u;
  ((unsigned*)sAlp)[tid + 256] = 0u;

  // ---- Phase A: gelu + split-bf16 into swizzled LDS (b1 pre-folded) ----
  {
    const int k0 = (tid & 127) * 2;
    const int pb = (tid >> 7) * 16;
    const float2 hiv = *(const float2*)(Hcat + (size_t)blk * 512 + k0);
    const float hx = hiv.x;
    const float hy = hiv.y;
    const float* hjp = Hcat + ((size_t)b * KK + pb) * 512 + 256 + k0;
    unsigned* aH = (unsigned*)sAh;
    unsigned* aL = (unsigned*)u.Al;
    const int cw = tid & 127;
#pragma unroll 4
    for (int p = 0; p < 16; ++p) {
      const int row = pb + p;
      float2 hj = *(const float2*)(hjp + (size_t)p * 512);
      float g0 = gelu_exact(hx + hj.x);
      float g1 = gelu_exact(hy + hj.y);
      unsigned h01 = cvt_pk_bf16(g0, g1);
      float h0f = __uint_as_float(h01 << 16);
      float h1f = __uint_as_float(h01 & 0xFFFF0000u);
      unsigned l01 = cvt_pk_bf16(g0 - h0f, g1 - h1f);
      const int wi = row * 128 + ((cw ^ ((row & 7) << 2)));
      aH[wi] = h01;
      aL[wi] = l01;
    }
  }
  __syncthreads();  // barrier 1

  // ---- Phase G: swapped e-GEMM (e^T fragments, clean loop) ----
  const int lane = tid & 63;
  const int wv = tid >> 6;  // wave owns e-cols nb..nb+31
  const int nb = wv * 32;
  const int l4 = lane >> 4;
  const int l15 = lane & 15;

  // eacc[w][a]: lane holds e[row = a*16 + l15][cols = nb + w*16 + l4*4 .. +3]
  f32x4 eacc[2][2];
#pragma unroll
  for (int w = 0; w < 2; ++w)
#pragma unroll
    for (int a = 0; a < 2; ++a)
      eacc[w][a] = (f32x4){0.f, 0.f, 0.f, 0.f};

  const int sw = (l15 & 7) << 4;
  const char* pAh = (const char*)sAh;
  const char* pAl = (const char*)u.Al;
  const size_t gB0 = (size_t)(nb + l15) * 256 + l4 * 8;

#pragma unroll
  for (int ks = 0; ks < 8; ++ks) {
    const int cbyte = ks * 64 + l4 * 16;
    const int o0 = l15 * 512 + (cbyte ^ sw);
    const int o1 = (16 + l15) * 512 + (cbyte ^ sw);
    s16x8 ah0 = *(const s16x8*)(pAh + o0);
    s16x8 ah1 = *(const s16x8*)(pAh + o1);
    s16x8 al0 = *(const s16x8*)(pAl + o0);
    s16x8 al1 = *(const s16x8*)(pAl + o1);
    const size_t g0 = gB0 + ks * 32;
    const size_t g1 = g0 + 16 * 256;
    s16x8 bh0 = *(const s16x8*)(Wh + g0);
    s16x8 bh1 = *(const s16x8*)(Wh + g1);
    s16x8 bl0 = *(const s16x8*)(Wl + g0);
    s16x8 bl1 = *(const s16x8*)(Wl + g1);

    // e^T = W^T A^T, 3-pass split: (Wh,Ah)+(Wh,Al)+(Wl,Ah)
    MFMA16(eacc[0][0], bh0, ah0); MFMA16(eacc[0][0], bh0, al0);
    MFMA16(eacc[0][0], bl0, ah0);
    MFMA16(eacc[0][1], bh0, ah1); MFMA16(eacc[0][1], bh0, al1);
    MFMA16(eacc[0][1], bl0, ah1);
    MFMA16(eacc[1][0], bh1, ah0); MFMA16(eacc[1][0], bh1, al0);
    MFMA16(eacc[1][0], bl1, ah0);
    MFMA16(eacc[1][1], bh1, ah1); MFMA16(eacc[1][1], bh1, al1);
    MFMA16(eacc[1][1], bl1, ah1);
  }

  __syncthreads();  // barrier 2: A-bufs consumed; u.e may be written

  // ---- Phase E: +b2, float4 e to global; split bf16 -> LDS (b64 writes) ----
  {
    const float4 b2q0 = *(const float4*)(b2 + nb + l4 * 4);
    const float4 b2q1 = *(const float4*)(b2 + nb + 16 + l4 * 4);
    float* eg = out + O2 + (size_t)blk * (KK * DD);
    char* pEh = (char*)u.e.Eh;
    char* pEl = (char*)u.e.El;
#pragma unroll
    for (int a = 0; a < 2; ++a) {
      const int row = a * 16 + l15;
      const int rsw = (row & 7) << 4;
#pragma unroll
      for (int w = 0; w < 2; ++w) {
        const float4 bq = w ? b2q1 : b2q0;
        float4 v = make_float4(eacc[w][a][0] + bq.x, eacc[w][a][1] + bq.y,
                               eacc[w][a][2] + bq.z, eacc[w][a][3] + bq.w);
        const int c0 = nb + w * 16 + l4 * 4;
        *(float4*)(eg + row * 128 + c0) = v;
        unsigned hp0 = cvt_pk_bf16(v.x, v.y);
        unsigned hp1 = cvt_pk_bf16(v.z, v.w);
        float f0 = __uint_as_float(hp0 << 16);
        float f1 = __uint_as_float(hp0 & 0xFFFF0000u);
        float f2 = __uint_as_float(hp1 << 16);
        float f3 = __uint_as_float(hp1 & 0xFFFF0000u);
        unsigned lp0 = cvt_pk_bf16(v.x - f0, v.y - f1);
        unsigned lp1 = cvt_pk_bf16(v.z - f2, v.w - f3);
        const int off = row * 256 + ((c0 * 2) ^ rsw);
        *(uint2*)(pEh + off) = make_uint2(hp0, hp1);
        *(uint2*)(pEl + off) = make_uint2(lp0, lp1);
      }
    }
  }
  __syncthreads();  // barrier 3

  // ---- Phase L: logits via MFMA K=128 (waves 0,1), softmax in-register ----
  if (wv < 2) {
    const int mrow = wv * 16;
    f32x4 lacc = (f32x4){0.f, 0.f, 0.f, 0.f};
    const char* pEh = (const char*)u.e.Eh;
    const char* pEl = (const char*)u.e.El;
    const int rowa = mrow + l15;
    const int rsw = (rowa & 7) << 4;
#pragma unroll
    for (int ks = 0; ks < 4; ++ks) {
      const int cbyte = ks * 64 + l4 * 16;
      const int o = rowa * 256 + (cbyte ^ rsw);
      s16x8 eh = *(const s16x8*)(pEh + o);
      s16x8 el = *(const s16x8*)(pEl + o);
      const size_t g = (size_t)l15 * 128 + ks * 32 + l4 * 8;
      s16x8 ch = *(const s16x8*)(cbh + g);
      s16x8 cl = *(const s16x8*)(cbl + g);
      MFMA16(lacc, eh, ch);
      MFMA16(lacc, el, ch);
      MFMA16(lacc, eh, cl);
    }
    float* lg_out = out + O3 + (size_t)blk * (KK * NN);
    float* ag_out = out + O1 + (size_t)blk * (KK * NN);
#pragma unroll
    for (int r = 0; r < 4; ++r) {
      const int row = mrow + l4 * 4 + r;
      float lg = lacc[r] * 10.0f;
      float mx = lg;
#pragma unroll
      for (int m = 1; m < 16; m <<= 1) mx = fmaxf(mx, __shfl_xor(mx, m));
      float p = __expf(lg - mx);
      float s = p;
#pragma unroll
      for (int m = 1; m < 16; m <<= 1) s += __shfl_xor(s, m);
      float a = p / s;
      lg_out[row * 16 + l15] = lg;
      ag_out[row * 16 + l15] = a;
      sAlp[row * 32 + l15] = f2bf(a);
    }
  }
  __syncthreads();  // barrier 4

  // ---- Phase M: m^T = cbT x alpha^T (swapped), float4 stores ----
  // wave wv covers c-tiles {wv, wv+4} for both j-tiles: 4 MFMA + 4 float4.
  {
#pragma unroll
    for (int jt = 0; jt < 2; ++jt) {
      s16x8 af = *(const s16x8*)(sAlp + (jt * 16 + l15) * 32 + l4 * 8);
      float* mg = out + O0 + (size_t)blk * (KK * DD) + (size_t)(jt * 16 + l15) * DD;
#pragma unroll
      for (int cp = 0; cp < 2; ++cp) {
        const int cc = wv + cp * 4;
        s16x8 cf = *(const s16x8*)(cbT + (size_t)(cc * 16 + l15) * 32 + l4 * 8);
        f32x4 mac = (f32x4){0.f, 0.f, 0.f, 0.f};
        MFMA16(mac, cf, af);  // lane: m[j = jt*16+l15][c = cc*16 + l4*4 + r]
        *(float4*)(mg + cc * 16 + l4 * 4) = *(float4*)&mac;
      }
    }
  }
}

extern "C" void kernel_launch(void* const* d_in, const int* in_sizes, int n_in,
                              void* d_out, int out_size, void* d_ws, size_t ws_size,
                              hipStream_t stream) {
  const float* z  = (const float*)d_in[0];   // (256,32,128)
  const float* W1 = (const float*)d_in[1];   // (256,256)
  const float* b1 = (const float*)d_in[2];   // (256,)
  const float* W2 = (const float*)d_in[3];   // (256,128)
  const float* b2 = (const float*)d_in[4];   // (128,)
  const float* cb = (const float*)d_in[5];   // (16,128)
  float* out = (float*)d_out;

  // ws: Hcat fp32 [8192][512] | zb | W1th | W1tl | Wh | Wl | cbh | cbl | cbT
  float* Hcat = (float*)d_ws;
  short* zb   = (short*)(Hcat + (size_t)8192 * 512);
  short* W1th = zb + (size_t)1048576;
  short* W1tl = W1th + (size_t)65536;
  short* Wh   = W1tl + (size_t)65536;
  short* Wl   = Wh + (size_t)32768;
  short* cbh  = Wl + (size_t)32768;
  short* cbl  = cbh + (size_t)2048;
  short* cbT  = cbl + (size_t)2048;

  prep_kernel<<<4096, 256, 0, stream>>>(z, W1, W2, cb, zb, W1th, W1tl, Wh, Wl,
                                        cbh, cbl, cbT);
  hproj_mfma<<<dim3(256, 4), 256, 0, stream>>>(zb, W1th, W1tl, b1, Hcat);
  pair_kernel<<<BB * KK, 256, 0, stream>>>(Hcat, Wh, Wl, b2, cbh, cbl, cbT, out);
}

// Round 14
// 196.229 us; speedup vs baseline: 1.8098x; 1.0337x over previous
//
#include <hip/hip_runtime.h>
#include <hip/hip_bf16.h>
#include <math.h>

// Problem constants
#define BB 256
#define KK 32
#define DD 128
#define HH 256
#define NN 16
// d_out layout (fp32, concatenated in return order)
#define O0 ((size_t)0)
#define O1 ((size_t)33554432)
#define O2 ((size_t)37748736)
#define O3 ((size_t)71303168)

typedef float f32x4 __attribute__((ext_vector_type(4)));
typedef short s16x8 __attribute__((ext_vector_type(8)));

static __device__ __forceinline__ short f2bf(float x) {
  __hip_bfloat16 h = __float2bfloat16(x);
  return *reinterpret_cast<short*>(&h);
}
static __device__ __forceinline__ float bf2f(short s) {
  __hip_bfloat16 h;
  *reinterpret_cast<short*>(&h) = s;
  return __bfloat162float(h);
}
// pack 2 f32 -> 2 bf16 (RNE): lo16=bf16(a), hi16=bf16(b)
static __device__ __forceinline__ unsigned cvt_pk_bf16(float a, float b) {
  unsigned r;
  asm volatile("v_cvt_pk_bf16_f32 %0, %1, %2" : "=v"(r) : "v"(a), "v"(b));
  return r;
}

// exact-erf gelu via Abramowitz-Stegun 7.1.26 (|erf err| <= 1.5e-7)
static __device__ __forceinline__ float gelu_exact(float x) {
  float ax = fabsf(x) * 0.70710678118654752f;
  float t = __builtin_amdgcn_rcpf(fmaf(0.3275911f, ax, 1.0f));
  float p = fmaf(1.061405429f, t, -1.453152027f);
  p = fmaf(p, t, 1.421413741f);
  p = fmaf(p, t, -0.284496736f);
  p = fmaf(p, t, 0.254829592f);
  p *= t;
  float e = __expf(-ax * ax);
  float er = fmaf(-p, e, 1.0f);  // erf(|x|/sqrt2)
  er = copysignf(er, x);
  return 0.5f * x * (1.0f + er);
}

// ---------------------------------------------------------------------------
// Prep: z -> bf16; W1 -> transposed hi/lo bf16 [512][128];
//       W2 -> transposed hi/lo bf16 [128][256]; cb -> hi/lo [n][k];
//       cbT -> bf16 [c 128][n 32] (n>=16 zero, for Phase M MFMA).
// ---------------------------------------------------------------------------
__global__ __launch_bounds__(256) void prep_kernel(
    const float* __restrict__ z, const float* __restrict__ W1,
    const float* __restrict__ W2, const float* __restrict__ cb,
    short* __restrict__ zb, short* __restrict__ W1th, short* __restrict__ W1tl,
    short* __restrict__ Wh, short* __restrict__ Wl,
    short* __restrict__ cbh, short* __restrict__ cbl, short* __restrict__ cbT) {
  const int idx = blockIdx.x * 256 + threadIdx.x;  // 1,048,576 total
  zb[idx] = f2bf(z[idx]);
  if (idx < 512 * 128) {  // W1t
    int c = idx >> 7, k = idx & 127;
    float w = (c < 256) ? W1[(size_t)k * 256 + c]
                        : W1[(size_t)(128 + k) * 256 + (c - 256)];
    short h = f2bf(w);
    W1th[idx] = h;
    W1tl[idx] = f2bf(w - bf2f(h));
  }
  if (idx < 128 * 256) {  // W2t: [c][k]
    int c = idx >> 8, k = idx & 255;
    float w = W2[(size_t)k * 128 + c];
    short h = f2bf(w);
    Wh[idx] = h;
    Wl[idx] = f2bf(w - bf2f(h));
  }
  if (idx < 2048) {  // cb [n][k] splits
    float v = cb[idx];
    short h = f2bf(v);
    cbh[idx] = h;
    cbl[idx] = f2bf(v - bf2f(h));
  }
  if (idx < 128 * 32) {  // cbT [c][n], zero-padded n>=16
    int c = idx >> 5, n = idx & 31;
    cbT[idx] = (n < 16) ? f2bf(cb[(size_t)n * 128 + c]) : (short)0;
  }
}

// ---------------------------------------------------------------------------
// H projection via MFMA: Hcat[8192][512] = zb @ W1t^T (split-bf16), b1 folded.
// ---------------------------------------------------------------------------
__global__ __launch_bounds__(256) void hproj_mfma(
    const short* __restrict__ zb, const short* __restrict__ W1th,
    const short* __restrict__ W1tl, const float* __restrict__ b1,
    float* __restrict__ H) {
  const int tid = threadIdx.x;
  const int lane = tid & 63;
  const int wv = tid >> 6;
  const int l4 = lane >> 4, l15 = lane & 15;
  const int row0 = blockIdx.x * 32;
  const int col0 = blockIdx.y * 128 + wv * 32;

  f32x4 acc[2][2];
#pragma unroll
  for (int mt = 0; mt < 2; ++mt)
#pragma unroll
    for (int nt = 0; nt < 2; ++nt)
      acc[mt][nt] = (f32x4){0.f, 0.f, 0.f, 0.f};

#pragma unroll
  for (int ks = 0; ks < 4; ++ks) {
    const int kof = ks * 32 + l4 * 8;
    s16x8 a0 = *(const s16x8*)(zb + (size_t)(row0 + l15) * 128 + kof);
    s16x8 a1 = *(const s16x8*)(zb + (size_t)(row0 + 16 + l15) * 128 + kof);
    s16x8 bh0 = *(const s16x8*)(W1th + (size_t)(col0 + l15) * 128 + kof);
    s16x8 bh1 = *(const s16x8*)(W1th + (size_t)(col0 + 16 + l15) * 128 + kof);
    s16x8 bl0 = *(const s16x8*)(W1tl + (size_t)(col0 + l15) * 128 + kof);
    s16x8 bl1 = *(const s16x8*)(W1tl + (size_t)(col0 + 16 + l15) * 128 + kof);
    acc[0][0] = __builtin_amdgcn_mfma_f32_16x16x32_bf16(a0, bh0, acc[0][0], 0, 0, 0);
    acc[0][0] = __builtin_amdgcn_mfma_f32_16x16x32_bf16(a0, bl0, acc[0][0], 0, 0, 0);
    acc[0][1] = __builtin_amdgcn_mfma_f32_16x16x32_bf16(a0, bh1, acc[0][1], 0, 0, 0);
    acc[0][1] = __builtin_amdgcn_mfma_f32_16x16x32_bf16(a0, bl1, acc[0][1], 0, 0, 0);
    acc[1][0] = __builtin_amdgcn_mfma_f32_16x16x32_bf16(a1, bh0, acc[1][0], 0, 0, 0);
    acc[1][0] = __builtin_amdgcn_mfma_f32_16x16x32_bf16(a1, bl0, acc[1][0], 0, 0, 0);
    acc[1][1] = __builtin_amdgcn_mfma_f32_16x16x32_bf16(a1, bh1, acc[1][1], 0, 0, 0);
    acc[1][1] = __builtin_amdgcn_mfma_f32_16x16x32_bf16(a1, bl1, acc[1][1], 0, 0, 0);
  }

#pragma unroll
  for (int nt = 0; nt < 2; ++nt) {
    const int col = col0 + nt * 16 + l15;
    const float bias = (col0 < 256) ? b1[col] : 0.f;  // wave-uniform branch
#pragma unroll
    for (int mt = 0; mt < 2; ++mt)
#pragma unroll
      for (int r = 0; r < 4; ++r)
        H[(size_t)(row0 + mt * 16 + l4 * 4 + r) * 512 + col] =
            acc[mt][nt][r] + bias;
  }
}

#define MFMA16(d, a, bsrc) d = __builtin_amdgcn_mfma_f32_16x16x32_bf16(a, bsrc, d, 0, 0, 0)

// ---------------------------------------------------------------------------
// Kernel B: one block (4 waves) per (b,i). Single-bf16 A (error ~7e-4 in e,
// two orders below the logits-path error that dominates absmax), W2 split.
//  A:  gelu(Hi+Hj) -> bf16 in swizzled LDS (16 KB only)
//  G:  swapped e-GEMM, 2-pass (Wh+Wl)xAh = 8 MFMA/ks
//  E:  e fp32 -> global float4; e hi/lo splits -> LDS (overlays dead Ah)
//  L:  logits = e @ cb^T via 3-pass MFMA K=128 (waves 0,1), softmax in-reg
//  M:  m^T = cbT x alpha^T swapped MFMA -> float4 stores
// LDS 18.8 KB -> 6 blocks/CU (launch_bounds(256,6), VGPR cap 85).
// XCD swizzle: same-b blocks share an XCD (Hj L2 reuse).
// ---------------------------------------------------------------------------
__global__ __launch_bounds__(256, 6) void pair_kernel(
    const float* __restrict__ Hcat, const short* __restrict__ Wh,
    const short* __restrict__ Wl, const float* __restrict__ b2,
    const short* __restrict__ cbh, const short* __restrict__ cbl,
    const short* __restrict__ cbT, float* __restrict__ out) {
  __shared__ union {
    short Ah[32 * 256];  // 16 KB gelu bf16, XOR-swizzled (dead after G)
    struct { short Eh[32 * 128]; short El[32 * 128]; } e;  // e splits, swizzled
  } u;
  __shared__ short sAlp[32 * 32];  // 2 KB alpha bf16, n zero-padded to 32

  const int tid = threadIdx.x;
  // bijective XCD swizzle (8192 % 8 == 0): same-b blocks share an XCD
  const int dd = blockIdx.x;
  const int blk = (dd & 7) * 1024 + (dd >> 3);  // = b*K + i
  const int b = blk >> 5;

  // zero-init alpha buffer (pad cols must be 0)
  ((unsigned*)sAlp)[tid] = 0u;
  ((unsigned*)sAlp)[tid + 256] = 0u;

  // ---- Phase A: gelu -> bf16 into swizzled LDS (b1 pre-folded) ----
  {
    const int k0 = (tid & 127) * 2;
    const int pb = (tid >> 7) * 16;
    const float2 hiv = *(const float2*)(Hcat + (size_t)blk * 512 + k0);
    const float hx = hiv.x;
    const float hy = hiv.y;
    const float* hjp = Hcat + ((size_t)b * KK + pb) * 512 + 256 + k0;
    unsigned* aH = (unsigned*)u.Ah;
    const int cw = tid & 127;
#pragma unroll 4
    for (int p = 0; p < 16; ++p) {
      const int row = pb + p;
      float2 hj = *(const float2*)(hjp + (size_t)p * 512);
      float g0 = gelu_exact(hx + hj.x);
      float g1 = gelu_exact(hy + hj.y);
      const int wi = row * 128 + ((cw ^ ((row & 7) << 2)));
      aH[wi] = cvt_pk_bf16(g0, g1);
    }
  }
  __syncthreads();  // barrier 1

  // ---- Phase G: swapped e-GEMM, 2-pass split-W (8 MFMA/ks) ----
  const int lane = tid & 63;
  const int wv = tid >> 6;  // wave owns e-cols nb..nb+31
  const int nb = wv * 32;
  const int l4 = lane >> 4;
  const int l15 = lane & 15;

  // eacc[w][a]: lane holds e[row = a*16 + l15][cols = nb + w*16 + l4*4 .. +3]
  f32x4 eacc[2][2];
#pragma unroll
  for (int w = 0; w < 2; ++w)
#pragma unroll
    for (int a = 0; a < 2; ++a)
      eacc[w][a] = (f32x4){0.f, 0.f, 0.f, 0.f};

  const int sw = (l15 & 7) << 4;
  const char* pAh = (const char*)u.Ah;
  const size_t gB0 = (size_t)(nb + l15) * 256 + l4 * 8;

#pragma unroll
  for (int ks = 0; ks < 8; ++ks) {
    const int cbyte = ks * 64 + l4 * 16;
    const int o0 = l15 * 512 + (cbyte ^ sw);
    const int o1 = (16 + l15) * 512 + (cbyte ^ sw);
    s16x8 ah0 = *(const s16x8*)(pAh + o0);
    s16x8 ah1 = *(const s16x8*)(pAh + o1);
    const size_t g0 = gB0 + ks * 32;
    const size_t g1 = g0 + 16 * 256;
    s16x8 bh0 = *(const s16x8*)(Wh + g0);
    s16x8 bh1 = *(const s16x8*)(Wh + g1);
    s16x8 bl0 = *(const s16x8*)(Wl + g0);
    s16x8 bl1 = *(const s16x8*)(Wl + g1);

    // e^T = (Wh + Wl)^T Ah^T
    MFMA16(eacc[0][0], bh0, ah0); MFMA16(eacc[0][0], bl0, ah0);
    MFMA16(eacc[0][1], bh0, ah1); MFMA16(eacc[0][1], bl0, ah1);
    MFMA16(eacc[1][0], bh1, ah0); MFMA16(eacc[1][0], bl1, ah0);
    MFMA16(eacc[1][1], bh1, ah1); MFMA16(eacc[1][1], bl1, ah1);
  }

  __syncthreads();  // barrier 2: Ah consumed by all waves; u.e may be written

  // ---- Phase E: +b2, float4 e to global; split bf16 -> LDS (b64 writes) ----
  {
    const float4 b2q0 = *(const float4*)(b2 + nb + l4 * 4);
    const float4 b2q1 = *(const float4*)(b2 + nb + 16 + l4 * 4);
    float* eg = out + O2 + (size_t)blk * (KK * DD);
    char* pEh = (char*)u.e.Eh;
    char* pEl = (char*)u.e.El;
#pragma unroll
    for (int a = 0; a < 2; ++a) {
      const int row = a * 16 + l15;
      const int rsw = (row & 7) << 4;
#pragma unroll
      for (int w = 0; w < 2; ++w) {
        const float4 bq = w ? b2q1 : b2q0;
        float4 v = make_float4(eacc[w][a][0] + bq.x, eacc[w][a][1] + bq.y,
                               eacc[w][a][2] + bq.z, eacc[w][a][3] + bq.w);
        const int c0 = nb + w * 16 + l4 * 4;
        *(float4*)(eg + row * 128 + c0) = v;
        unsigned hp0 = cvt_pk_bf16(v.x, v.y);
        unsigned hp1 = cvt_pk_bf16(v.z, v.w);
        float f0 = __uint_as_float(hp0 << 16);
        float f1 = __uint_as_float(hp0 & 0xFFFF0000u);
        float f2 = __uint_as_float(hp1 << 16);
        float f3 = __uint_as_float(hp1 & 0xFFFF0000u);
        unsigned lp0 = cvt_pk_bf16(v.x - f0, v.y - f1);
        unsigned lp1 = cvt_pk_bf16(v.z - f2, v.w - f3);
        const int off = row * 256 + ((c0 * 2) ^ rsw);
        *(uint2*)(pEh + off) = make_uint2(hp0, hp1);
        *(uint2*)(pEl + off) = make_uint2(lp0, lp1);
      }
    }
  }
  __syncthreads();  // barrier 3

  // ---- Phase L: logits via 3-pass MFMA K=128 (waves 0,1), softmax in-reg ----
  if (wv < 2) {
    const int mrow = wv * 16;
    f32x4 lacc = (f32x4){0.f, 0.f, 0.f, 0.f};
    const char* pEh = (const char*)u.e.Eh;
    const char* pEl = (const char*)u.e.El;
    const int rowa = mrow + l15;
    const int rsw = (rowa & 7) << 4;
#pragma unroll
    for (int ks = 0; ks < 4; ++ks) {
      const int cbyte = ks * 64 + l4 * 16;
      const int o = rowa * 256 + (cbyte ^ rsw);
      s16x8 eh = *(const s16x8*)(pEh + o);
      s16x8 el = *(const s16x8*)(pEl + o);
      const size_t g = (size_t)l15 * 128 + ks * 32 + l4 * 8;
      s16x8 ch = *(const s16x8*)(cbh + g);
      s16x8 cl = *(const s16x8*)(cbl + g);
      MFMA16(lacc, eh, ch);
      MFMA16(lacc, el, ch);
      MFMA16(lacc, eh, cl);
    }
    float* lg_out = out + O3 + (size_t)blk * (KK * NN);
    float* ag_out = out + O1 + (size_t)blk * (KK * NN);
#pragma unroll
    for (int r = 0; r < 4; ++r) {
      const int row = mrow + l4 * 4 + r;
      float lg = lacc[r] * 10.0f;
      float mx = lg;
#pragma unroll
      for (int m = 1; m < 16; m <<= 1) mx = fmaxf(mx, __shfl_xor(mx, m));
      float p = __expf(lg - mx);
      float s = p;
#pragma unroll
      for (int m = 1; m < 16; m <<= 1) s += __shfl_xor(s, m);
      float a = p / s;
      lg_out[row * 16 + l15] = lg;
      ag_out[row * 16 + l15] = a;
      sAlp[row * 32 + l15] = f2bf(a);
    }
  }
  __syncthreads();  // barrier 4

  // ---- Phase M: m^T = cbT x alpha^T (swapped), float4 stores ----
  {
#pragma unroll
    for (int jt = 0; jt < 2; ++jt) {
      s16x8 af = *(const s16x8*)(sAlp + (jt * 16 + l15) * 32 + l4 * 8);
      float* mg = out + O0 + (size_t)blk * (KK * DD) + (size_t)(jt * 16 + l15) * DD;
#pragma unroll
      for (int cp = 0; cp < 2; ++cp) {
        const int cc = wv + cp * 4;
        s16x8 cf = *(const s16x8*)(cbT + (size_t)(cc * 16 + l15) * 32 + l4 * 8);
        f32x4 mac = (f32x4){0.f, 0.f, 0.f, 0.f};
        MFMA16(mac, cf, af);  // lane: m[j = jt*16+l15][c = cc*16 + l4*4 + r]
        *(float4*)(mg + cc * 16 + l4 * 4) = *(float4*)&mac;
      }
    }
  }
}

extern "C" void kernel_launch(void* const* d_in, const int* in_sizes, int n_in,
                              void* d_out, int out_size, void* d_ws, size_t ws_size,
                              hipStream_t stream) {
  const float* z  = (const float*)d_in[0];   // (256,32,128)
  const float* W1 = (const float*)d_in[1];   // (256,256)
  const float* b1 = (const float*)d_in[2];   // (256,)
  const float* W2 = (const float*)d_in[3];   // (256,128)
  const float* b2 = (const float*)d_in[4];   // (128,)
  const float* cb = (const float*)d_in[5];   // (16,128)
  float* out = (float*)d_out;

  // ws: Hcat fp32 [8192][512] | zb | W1th | W1tl | Wh | Wl | cbh | cbl | cbT
  float* Hcat = (float*)d_ws;
  short* zb   = (short*)(Hcat + (size_t)8192 * 512);
  short* W1th = zb + (size_t)1048576;
  short* W1tl = W1th + (size_t)65536;
  short* Wh   = W1tl + (size_t)65536;
  short* Wl   = Wh + (size_t)32768;
  short* cbh  = Wl + (size_t)32768;
  short* cbl  = cbh + (size_t)2048;
  short* cbT  = cbl + (size_t)2048;

  prep_kernel<<<4096, 256, 0, stream>>>(z, W1, W2, cb, zb, W1th, W1tl, Wh, Wl,
                                        cbh, cbl, cbT);
  hproj_mfma<<<dim3(256, 4), 256, 0, stream>>>(zb, W1th, W1tl, b1, Hcat);
  pair_kernel<<<BB * KK, 256, 0, stream>>>(Hcat, Wh, Wl, b2, cbh, cbl, cbT, out);
}

// Round 15
// 195.913 us; speedup vs baseline: 1.8127x; 1.0016x over previous
//
#include <hip/hip_runtime.h>
#include <hip/hip_bf16.h>
#include <math.h>

// Problem constants
#define BB 256
#define KK 32
#define DD 128
#define HH 256
#define NN 16
// d_out layout (fp32, concatenated in return order)
#define O0 ((size_t)0)
#define O1 ((size_t)33554432)
#define O2 ((size_t)37748736)
#define O3 ((size_t)71303168)

typedef float f32x4 __attribute__((ext_vector_type(4)));
typedef short s16x8 __attribute__((ext_vector_type(8)));

static __device__ __forceinline__ short f2bf(float x) {
  __hip_bfloat16 h = __float2bfloat16(x);
  return *reinterpret_cast<short*>(&h);
}
static __device__ __forceinline__ float bf2f(short s) {
  __hip_bfloat16 h;
  *reinterpret_cast<short*>(&h) = s;
  return __bfloat162float(h);
}
// pack 2 f32 -> 2 bf16 (RNE): lo16=bf16(a), hi16=bf16(b)
static __device__ __forceinline__ unsigned cvt_pk_bf16(float a, float b) {
  unsigned r;
  asm volatile("v_cvt_pk_bf16_f32 %0, %1, %2" : "=v"(r) : "v"(a), "v"(b));
  return r;
}

// exact-erf gelu via Abramowitz-Stegun 7.1.26 (|erf err| <= 1.5e-7)
static __device__ __forceinline__ float gelu_exact(float x) {
  float ax = fabsf(x) * 0.70710678118654752f;
  float t = __builtin_amdgcn_rcpf(fmaf(0.3275911f, ax, 1.0f));
  float p = fmaf(1.061405429f, t, -1.453152027f);
  p = fmaf(p, t, 1.421413741f);
  p = fmaf(p, t, -0.284496736f);
  p = fmaf(p, t, 0.254829592f);
  p *= t;
  float e = __expf(-ax * ax);
  float er = fmaf(-p, e, 1.0f);  // erf(|x|/sqrt2)
  er = copysignf(er, x);
  return 0.5f * x * (1.0f + er);
}

// ---------------------------------------------------------------------------
// Prep: z -> bf16; W1 -> transposed hi/lo bf16 [512][128];
//       W2 -> transposed hi/lo bf16 [128][256]; cb -> hi/lo [n][k];
//       cbT -> bf16 [c 128][n 32] (n>=16 zero, for Phase M MFMA).
// ---------------------------------------------------------------------------
__global__ __launch_bounds__(256) void prep_kernel(
    const float* __restrict__ z, const float* __restrict__ W1,
    const float* __restrict__ W2, const float* __restrict__ cb,
    short* __restrict__ zb, short* __restrict__ W1th, short* __restrict__ W1tl,
    short* __restrict__ Wh, short* __restrict__ Wl,
    short* __restrict__ cbh, short* __restrict__ cbl, short* __restrict__ cbT) {
  const int idx = blockIdx.x * 256 + threadIdx.x;  // 1,048,576 total
  zb[idx] = f2bf(z[idx]);
  if (idx < 512 * 128) {  // W1t
    int c = idx >> 7, k = idx & 127;
    float w = (c < 256) ? W1[(size_t)k * 256 + c]
                        : W1[(size_t)(128 + k) * 256 + (c - 256)];
    short h = f2bf(w);
    W1th[idx] = h;
    W1tl[idx] = f2bf(w - bf2f(h));
  }
  if (idx < 128 * 256) {  // W2t: [c][k]
    int c = idx >> 8, k = idx & 255;
    float w = W2[(size_t)k * 128 + c];
    short h = f2bf(w);
    Wh[idx] = h;
    Wl[idx] = f2bf(w - bf2f(h));
  }
  if (idx < 2048) {  // cb [n][k] splits
    float v = cb[idx];
    short h = f2bf(v);
    cbh[idx] = h;
    cbl[idx] = f2bf(v - bf2f(h));
  }
  if (idx < 128 * 32) {  // cbT [c][n], zero-padded n>=16
    int c = idx >> 5, n = idx & 31;
    cbT[idx] = (n < 16) ? f2bf(cb[(size_t)n * 128 + c]) : (short)0;
  }
}

// ---------------------------------------------------------------------------
// H projection via MFMA: Hcat[8192][512] = zb @ W1t^T (split-bf16), b1 folded.
// ---------------------------------------------------------------------------
__global__ __launch_bounds__(256) void hproj_mfma(
    const short* __restrict__ zb, const short* __restrict__ W1th,
    const short* __restrict__ W1tl, const float* __restrict__ b1,
    float* __restrict__ H) {
  const int tid = threadIdx.x;
  const int lane = tid & 63;
  const int wv = tid >> 6;
  const int l4 = lane >> 4, l15 = lane & 15;
  const int row0 = blockIdx.x * 32;
  const int col0 = blockIdx.y * 128 + wv * 32;

  f32x4 acc[2][2];
#pragma unroll
  for (int mt = 0; mt < 2; ++mt)
#pragma unroll
    for (int nt = 0; nt < 2; ++nt)
      acc[mt][nt] = (f32x4){0.f, 0.f, 0.f, 0.f};

#pragma unroll
  for (int ks = 0; ks < 4; ++ks) {
    const int kof = ks * 32 + l4 * 8;
    s16x8 a0 = *(const s16x8*)(zb + (size_t)(row0 + l15) * 128 + kof);
    s16x8 a1 = *(const s16x8*)(zb + (size_t)(row0 + 16 + l15) * 128 + kof);
    s16x8 bh0 = *(const s16x8*)(W1th + (size_t)(col0 + l15) * 128 + kof);
    s16x8 bh1 = *(const s16x8*)(W1th + (size_t)(col0 + 16 + l15) * 128 + kof);
    s16x8 bl0 = *(const s16x8*)(W1tl + (size_t)(col0 + l15) * 128 + kof);
    s16x8 bl1 = *(const s16x8*)(W1tl + (size_t)(col0 + 16 + l15) * 128 + kof);
    acc[0][0] = __builtin_amdgcn_mfma_f32_16x16x32_bf16(a0, bh0, acc[0][0], 0, 0, 0);
    acc[0][0] = __builtin_amdgcn_mfma_f32_16x16x32_bf16(a0, bl0, acc[0][0], 0, 0, 0);
    acc[0][1] = __builtin_amdgcn_mfma_f32_16x16x32_bf16(a0, bh1, acc[0][1], 0, 0, 0);
    acc[0][1] = __builtin_amdgcn_mfma_f32_16x16x32_bf16(a0, bl1, acc[0][1], 0, 0, 0);
    acc[1][0] = __builtin_amdgcn_mfma_f32_16x16x32_bf16(a1, bh0, acc[1][0], 0, 0, 0);
    acc[1][0] = __builtin_amdgcn_mfma_f32_16x16x32_bf16(a1, bl0, acc[1][0], 0, 0, 0);
    acc[1][1] = __builtin_amdgcn_mfma_f32_16x16x32_bf16(a1, bh1, acc[1][1], 0, 0, 0);
    acc[1][1] = __builtin_amdgcn_mfma_f32_16x16x32_bf16(a1, bl1, acc[1][1], 0, 0, 0);
  }

#pragma unroll
  for (int nt = 0; nt < 2; ++nt) {
    const int col = col0 + nt * 16 + l15;
    const float bias = (col0 < 256) ? b1[col] : 0.f;  // wave-uniform branch
#pragma unroll
    for (int mt = 0; mt < 2; ++mt)
#pragma unroll
      for (int r = 0; r < 4; ++r)
        H[(size_t)(row0 + mt * 16 + l4 * 4 + r) * 512 + col] =
            acc[mt][nt][r] + bias;
  }
}

#define MFMA16(d, a, bsrc) d = __builtin_amdgcn_mfma_f32_16x16x32_bf16(a, bsrc, d, 0, 0, 0)

// ---------------------------------------------------------------------------
// Kernel B: one block (4 waves) per (b,i). Single-bf16 A, split W2.
//  A:  gelu(Hi+Hj) -> bf16 in swizzled LDS (16 KB)
//  G:  swapped e-GEMM, 2-pass (Wh+Wl)xAh = 8 MFMA/ks
//  E:  e fp32 -> global float4; e hi/lo splits -> LDS (overlays dead Ah)
//  L:  logits = e @ cb^T via 3-pass MFMA K=128 (waves 0,1), softmax in-reg
//  M:  m^T = cbT x alpha^T swapped MFMA -> float4 stores
// LDS 18.4 KB, VGPR ~40 -> EIGHT blocks/CU (launch_bounds(256,8), cap 64,
// measured usage 40 so no allocator squeeze; 8x18.4=147KB < 160KB).
// XCD swizzle: same-b blocks share an XCD (Hj L2 reuse).
// ---------------------------------------------------------------------------
__global__ __launch_bounds__(256, 8) void pair_kernel(
    const float* __restrict__ Hcat, const short* __restrict__ Wh,
    const short* __restrict__ Wl, const float* __restrict__ b2,
    const short* __restrict__ cbh, const short* __restrict__ cbl,
    const short* __restrict__ cbT, float* __restrict__ out) {
  __shared__ union {
    short Ah[32 * 256];  // 16 KB gelu bf16, XOR-swizzled (dead after G)
    struct { short Eh[32 * 128]; short El[32 * 128]; } e;  // e splits, swizzled
  } u;
  __shared__ short sAlp[32 * 32];  // 2 KB alpha bf16, n zero-padded to 32

  const int tid = threadIdx.x;
  // bijective XCD swizzle (8192 % 8 == 0): same-b blocks share an XCD
  const int dd = blockIdx.x;
  const int blk = (dd & 7) * 1024 + (dd >> 3);  // = b*K + i
  const int b = blk >> 5;

  // ---- Phase A: gelu -> bf16 into swizzled LDS (b1 pre-folded) ----
  {
    const int k0 = (tid & 127) * 2;
    const int pb = (tid >> 7) * 16;
    const float2 hiv = *(const float2*)(Hcat + (size_t)blk * 512 + k0);
    const float hx = hiv.x;
    const float hy = hiv.y;
    const float* hjp = Hcat + ((size_t)b * KK + pb) * 512 + 256 + k0;
    unsigned* aH = (unsigned*)u.Ah;
    const int cw = tid & 127;
    // zero-init alpha buffer (needed before Phase L, not before A)
    ((unsigned*)sAlp)[tid] = 0u;
    ((unsigned*)sAlp)[tid + 256] = 0u;
#pragma unroll 4
    for (int p = 0; p < 16; ++p) {
      const int row = pb + p;
      float2 hj = *(const float2*)(hjp + (size_t)p * 512);
      float g0 = gelu_exact(hx + hj.x);
      float g1 = gelu_exact(hy + hj.y);
      const int wi = row * 128 + ((cw ^ ((row & 7) << 2)));
      aH[wi] = cvt_pk_bf16(g0, g1);
    }
  }
  __syncthreads();  // barrier 1

  // ---- Phase G: swapped e-GEMM, 2-pass split-W (8 MFMA/ks) ----
  const int lane = tid & 63;
  const int wv = tid >> 6;  // wave owns e-cols nb..nb+31
  const int nb = wv * 32;
  const int l4 = lane >> 4;
  const int l15 = lane & 15;

  // eacc[w][a]: lane holds e[row = a*16 + l15][cols = nb + w*16 + l4*4 .. +3]
  f32x4 eacc[2][2];
#pragma unroll
  for (int w = 0; w < 2; ++w)
#pragma unroll
    for (int a = 0; a < 2; ++a)
      eacc[w][a] = (f32x4){0.f, 0.f, 0.f, 0.f};

  const int sw = (l15 & 7) << 4;
  const char* pAh = (const char*)u.Ah;
  const size_t gB0 = (size_t)(nb + l15) * 256 + l4 * 8;

#pragma unroll
  for (int ks = 0; ks < 8; ++ks) {
    const int cbyte = ks * 64 + l4 * 16;
    const int o0 = l15 * 512 + (cbyte ^ sw);
    const int o1 = (16 + l15) * 512 + (cbyte ^ sw);
    s16x8 ah0 = *(const s16x8*)(pAh + o0);
    s16x8 ah1 = *(const s16x8*)(pAh + o1);
    const size_t g0 = gB0 + ks * 32;
    const size_t g1 = g0 + 16 * 256;
    s16x8 bh0 = *(const s16x8*)(Wh + g0);
    s16x8 bh1 = *(const s16x8*)(Wh + g1);
    s16x8 bl0 = *(const s16x8*)(Wl + g0);
    s16x8 bl1 = *(const s16x8*)(Wl + g1);

    // e^T = (Wh + Wl)^T Ah^T
    MFMA16(eacc[0][0], bh0, ah0); MFMA16(eacc[0][0], bl0, ah0);
    MFMA16(eacc[0][1], bh0, ah1); MFMA16(eacc[0][1], bl0, ah1);
    MFMA16(eacc[1][0], bh1, ah0); MFMA16(eacc[1][0], bl1, ah0);
    MFMA16(eacc[1][1], bh1, ah1); MFMA16(eacc[1][1], bl1, ah1);
  }

  __syncthreads();  // barrier 2: Ah consumed by all waves; u.e may be written

  // ---- Phase E: +b2, float4 e to global; split bf16 -> LDS (b64 writes) ----
  {
    const float4 b2q0 = *(const float4*)(b2 + nb + l4 * 4);
    const float4 b2q1 = *(const float4*)(b2 + nb + 16 + l4 * 4);
    float* eg = out + O2 + (size_t)blk * (KK * DD);
    char* pEh = (char*)u.e.Eh;
    char* pEl = (char*)u.e.El;
#pragma unroll
    for (int a = 0; a < 2; ++a) {
      const int row = a * 16 + l15;
      const int rsw = (row & 7) << 4;
#pragma unroll
      for (int w = 0; w < 2; ++w) {
        const float4 bq = w ? b2q1 : b2q0;
        float4 v = make_float4(eacc[w][a][0] + bq.x, eacc[w][a][1] + bq.y,
                               eacc[w][a][2] + bq.z, eacc[w][a][3] + bq.w);
        const int c0 = nb + w * 16 + l4 * 4;
        *(float4*)(eg + row * 128 + c0) = v;
        unsigned hp0 = cvt_pk_bf16(v.x, v.y);
        unsigned hp1 = cvt_pk_bf16(v.z, v.w);
        float f0 = __uint_as_float(hp0 << 16);
        float f1 = __uint_as_float(hp0 & 0xFFFF0000u);
        float f2 = __uint_as_float(hp1 << 16);
        float f3 = __uint_as_float(hp1 & 0xFFFF0000u);
        unsigned lp0 = cvt_pk_bf16(v.x - f0, v.y - f1);
        unsigned lp1 = cvt_pk_bf16(v.z - f2, v.w - f3);
        const int off = row * 256 + ((c0 * 2) ^ rsw);
        *(uint2*)(pEh + off) = make_uint2(hp0, hp1);
        *(uint2*)(pEl + off) = make_uint2(lp0, lp1);
      }
    }
  }
  __syncthreads();  // barrier 3

  // ---- Phase L: logits via 3-pass MFMA K=128 (waves 0,1), softmax in-reg ----
  if (wv < 2) {
    const int mrow = wv * 16;
    f32x4 lacc = (f32x4){0.f, 0.f, 0.f, 0.f};
    const char* pEh = (const char*)u.e.Eh;
    const char* pEl = (const char*)u.e.El;
    const int rowa = mrow + l15;
    const int rsw = (rowa & 7) << 4;
#pragma unroll
    for (int ks = 0; ks < 4; ++ks) {
      const int cbyte = ks * 64 + l4 * 16;
      const int o = rowa * 256 + (cbyte ^ rsw);
      s16x8 eh = *(const s16x8*)(pEh + o);
      s16x8 el = *(const s16x8*)(pEl + o);
      const size_t g = (size_t)l15 * 128 + ks * 32 + l4 * 8;
      s16x8 ch = *(const s16x8*)(cbh + g);
      s16x8 cl = *(const s16x8*)(cbl + g);
      MFMA16(lacc, eh, ch);
      MFMA16(lacc, el, ch);
      MFMA16(lacc, eh, cl);
    }
    float* lg_out = out + O3 + (size_t)blk * (KK * NN);
    float* ag_out = out + O1 + (size_t)blk * (KK * NN);
#pragma unroll
    for (int r = 0; r < 4; ++r) {
      const int row = mrow + l4 * 4 + r;
      float lg = lacc[r] * 10.0f;
      float mx = lg;
#pragma unroll
      for (int m = 1; m < 16; m <<= 1) mx = fmaxf(mx, __shfl_xor(mx, m));
      float p = __expf(lg - mx);
      float s = p;
#pragma unroll
      for (int m = 1; m < 16; m <<= 1) s += __shfl_xor(s, m);
      float a = p / s;
      lg_out[row * 16 + l15] = lg;
      ag_out[row * 16 + l15] = a;
      sAlp[row * 32 + l15] = f2bf(a);
    }
  }
  __syncthreads();  // barrier 4

  // ---- Phase M: m^T = cbT x alpha^T (swapped), float4 stores ----
  {
#pragma unroll
    for (int jt = 0; jt < 2; ++jt) {
      s16x8 af = *(const s16x8*)(sAlp + (jt * 16 + l15) * 32 + l4 * 8);
      float* mg = out + O0 + (size_t)blk * (KK * DD) + (size_t)(jt * 16 + l15) * DD;
#pragma unroll
      for (int cp = 0; cp < 2; ++cp) {
        const int cc = wv + cp * 4;
        s16x8 cf = *(const s16x8*)(cbT + (size_t)(cc * 16 + l15) * 32 + l4 * 8);
        f32x4 mac = (f32x4){0.f, 0.f, 0.f, 0.f};
        MFMA16(mac, cf, af);  // lane: m[j = jt*16+l15][c = cc*16 + l4*4 + r]
        *(float4*)(mg + cc * 16 + l4 * 4) = *(float4*)&mac;
      }
    }
  }
}

extern "C" void kernel_launch(void* const* d_in, const int* in_sizes, int n_in,
                              void* d_out, int out_size, void* d_ws, size_t ws_size,
                              hipStream_t stream) {
  const float* z  = (const float*)d_in[0];   // (256,32,128)
  const float* W1 = (const float*)d_in[1];   // (256,256)
  const float* b1 = (const float*)d_in[2];   // (256,)
  const float* W2 = (const float*)d_in[3];   // (256,128)
  const float* b2 = (const float*)d_in[4];   // (128,)
  const float* cb = (const float*)d_in[5];   // (16,128)
  float* out = (float*)d_out;

  // ws: Hcat fp32 [8192][512] | zb | W1th | W1tl | Wh | Wl | cbh | cbl | cbT
  float* Hcat = (float*)d_ws;
  short* zb   = (short*)(Hcat + (size_t)8192 * 512);
  short* W1th = zb + (size_t)1048576;
  short* W1tl = W1th + (size_t)65536;
  short* Wh   = W1tl + (size_t)65536;
  short* Wl   = Wh + (size_t)32768;
  short* cbh  = Wl + (size_t)32768;
  short* cbl  = cbh + (size_t)2048;
  short* cbT  = cbl + (size_t)2048;

  prep_kernel<<<4096, 256, 0, stream>>>(z, W1, W2, cb, zb, W1th, W1tl, Wh, Wl,
                                        cbh, cbl, cbT);
  hproj_mfma<<<dim3(256, 4), 256, 0, stream>>>(zb, W1th, W1tl, b1, Hcat);
  pair_kernel<<<BB * KK, 256, 0, stream>>>(Hcat, Wh, Wl, b2, cbh, cbl, cbT, out);
}